// Round 9
// baseline (51.191 us; speedup 1.0000x reference)
//
#include <hip/hip_runtime.h>
#include <hip/hip_bf16.h>
#include <math.h>

// B=256, N=256, E=512, ITER=10
#define Bb   256
#define Nn   256
#define Ee   512
#define TKF  32             // k-elems per chunk (f32)
#define NCH  (Ee / TKF)     // 16 chunks
#define NITER 10

typedef __attribute__((ext_vector_type(8))) short bf16x8;   // MFMA A/B frag (4 VGPR)
typedef __attribute__((ext_vector_type(4))) float f32x4;    // MFMA C/D frag

typedef __attribute__((address_space(1))) const void glb_cv;
typedef __attribute__((address_space(3))) void lds_v;

// raw sync: DMA loads stay in flight ACROSS barriers (T3/T4); __syncthreads()
// would drain vmcnt(0) at every barrier.
#define VMCNT(n) asm volatile("s_waitcnt vmcnt(" #n ")" ::: "memory")
#define LGKM0()  asm volatile("s_waitcnt lgkmcnt(0)" ::: "memory")
#define SCHED0() __builtin_amdgcn_sched_barrier(0)

static __device__ __forceinline__ unsigned short f2bf(float f) {
    __hip_bfloat16 h = __float2bfloat16(f);     // RNE; pairs fuse to v_cvt_pk_bf16_f32
    return __builtin_bit_cast(unsigned short, h);
}

// bf16 tile: [256 rows][32 k], 64 B rows, XOR swizzle byte ^= (row&3)<<4.
// Frag read positions mod 128B spread over 8 distinct 16B slots x 8 lanes
// = full 32-bank coverage (minimum cycles for b128).
static __device__ __forceinline__ bf16x8 ldfrag(const unsigned char* bt, int row, int hi) {
    const int byte = row * 64 + ((hi * 16) ^ ((row & 3) << 4));
    return *reinterpret_cast<const bf16x8*>(bt + byte);
}

// ---------- Wsym = 0.5*(W + W^T): direct version (proven round 7) ----------
__global__ __launch_bounds__(256) void wsym_k(const float* __restrict__ W,
                                              float* __restrict__ wsym) {
    const int idx = blockIdx.x * 256 + threadIdx.x;   // 0..16383
    const int r  = idx >> 6;                          // row 0..255
    const int c0 = (idx & 63) * 4;                    // col group
    const float4 a = *reinterpret_cast<const float4*>(&W[r * Nn + c0]);
    float4 o;
    o.x = 0.5f * (a.x + W[(c0 + 0) * Nn + r]);
    o.y = 0.5f * (a.y + W[(c0 + 1) * Nn + r]);
    o.z = 0.5f * (a.z + W[(c0 + 2) * Nn + r]);
    o.w = 0.5f * (a.w + W[(c0 + 3) * Nn + r]);
    *reinterpret_cast<float4*>(&wsym[r * Nn + c0]) = o;
}

// 512 threads = 8 waves (4x2); wave (wr,wc) owns rows [wr*64,+64) x cols
// [wc*128,+128) of C = F F^T.  acc[4][8] f32x4 = 128 accum regs; all acc
// indices compile-time (rule #20).
//
// K-loop: ONE barrier per chunk, 3-deep fstage, convert folded under MFMA.
// Invariant entering iter ch: conv(ch)->btile[ch&1] visible to all waves;
// all waves' DMA(ch+1) arrived; own outstanding = DMA(ch+2) (4 loads).
//   stage(ch+3) -> slot[ch%3]      (slot conv(ch) emptied last iter)
//   mfma(ch)  ∥  conv(ch+1)        (VALU+LDS co-issues with MFMA pipe, m114)
//   lgkmcnt(0)                     (conv reads+writes drained)
//   vmcnt(4)                       (own DMA(ch+2) arrived; ch+3 in flight)
//   s_barrier                      (globalizes both -> invariant for ch+1)
template <bool USE_WS>
__global__ __launch_bounds__(512, 2) void crf_mfma(
    const float* __restrict__ feats,   // [B, N, E]
    const float* __restrict__ logits,  // [B, N, 1]
    const float* __restrict__ W,       // [1, N, N] (raw; used if !USE_WS)
    const float* __restrict__ wsym,    // [N, N] precomputed 0.5*(W+W^T)
    float* __restrict__ out)           // [B, N, 1]
{
    const int b    = blockIdx.x;
    const int t    = threadIdx.x;
    const int wave = t >> 6;           // 0..7
    const int lane = t & 63;
    const int wr   = wave >> 1;        // 0..3 (64-row block)
    const int wc   = wave & 1;         // 0..1 (128-col block)
    const int lo   = lane & 15;        // C/D col = lo; A/B row = lo
    const int hi   = lane >> 4;        // C/D row = hi*4+reg; A/B k-base = hi*8

    __shared__ float fstage[3][Nn * TKF];        // 3 x 32 KB linear f32 chunks
    __shared__ unsigned char btile[2][Nn * 64];  // 2 x 16 KB swizzled bf16 tiles
    __shared__ float invn[Nn];
    __shared__ float svec[Nn];
    __shared__ float uvec[Nn];
    __shared__ float lgv[Nn];
    __shared__ float part[4][Nn];

    f32x4 acc[4][8];
#pragma unroll
    for (int i = 0; i < 4; ++i)
#pragma unroll
        for (int j = 0; j < 8; ++j) acc[i][j] = (f32x4){0.f, 0.f, 0.f, 0.f};

    const float* Fb = feats + (size_t)b * Nn * Ee;

    // DMA chunk ch -> fstage[slot]: 4 x global_load_lds(16B)/wave (1 KB each).
    auto stage = [&](int ch, int slot) {
#pragma unroll
        for (int i = 0; i < 4; ++i) {
            const int gbase = wave * 4 + i;            // 1KB block id (0..31)
            const int row   = gbase * 8 + (lane >> 3); // per-lane row
            const float* src = Fb + (size_t)row * Ee + ch * TKF + (lane & 7) * 4;
            __builtin_amdgcn_global_load_lds((glb_cv*)src,
                                             (lds_v*)(&fstage[slot][gbase * 256]), 16, 0, 0);
        }
    };

    // convert fstage[slot] (f32) -> btile[buf] (bf16, swizzled).
    auto convert = [&](int slot, int buf) {
#pragma unroll
        for (int g = 0; g < 4; ++g) {
            const int m   = t + 512 * g;              // granule id (4 f32)
            const int row = m >> 3;
            const int gc  = m & 7;
            const float4 v = *reinterpret_cast<const float4*>(&fstage[slot][m * 4]);
            ushort4 pk;
            pk.x = f2bf(v.x); pk.y = f2bf(v.y); pk.z = f2bf(v.z); pk.w = f2bf(v.w);
            *reinterpret_cast<ushort4*>(
                &btile[buf][row * 64 + ((gc * 8) ^ ((row & 3) << 4))]) = pk;
        }
    };

    auto mfma_step = [&](int buf) {
        const unsigned char* tb = &btile[buf][0];
        bf16x8 af[4];
#pragma unroll
        for (int rb = 0; rb < 4; ++rb)
            af[rb] = ldfrag(tb, wr * 64 + rb * 16 + lo, hi);
#pragma unroll
        for (int cg = 0; cg < 2; ++cg) {
            bf16x8 bfv[4];
#pragma unroll
            for (int cq = 0; cq < 4; ++cq)
                bfv[cq] = ldfrag(tb, wc * 128 + (cg * 4 + cq) * 16 + lo, hi);
#pragma unroll
            for (int rb = 0; rb < 4; ++rb)
#pragma unroll
                for (int cq = 0; cq < 4; ++cq)
                    acc[rb][cg * 4 + cq] = __builtin_amdgcn_mfma_f32_16x16x32_bf16(
                        af[rb], bfv[cq], acc[rb][cg * 4 + cq], 0, 0, 0);
        }
    };

    // ---- prologue: logits first (oldest in queue), then 3 chunk DMAs ----
    float uval = 0.f;
    if (t < Nn) uval = logits[(size_t)b * Nn + t];
    stage(0, 0);
    stage(1, 1);
    stage(2, 2);
    if (t < Nn) {
        uvec[t] = uval;
        lgv[t]  = uval;
    }
    VMCNT(8);  SCHED0();                 // own DMA(0) arrived ({1,2} in flight)
    __builtin_amdgcn_s_barrier();        // -> all waves' DMA(0) arrived
    convert(0, 0);
    LGKM0();
    VMCNT(4);  SCHED0();                 // conv(0) drained; DMA(1) arrived
    __builtin_amdgcn_s_barrier();        // invariant for ch=0 established

    // ================= GEMM: C = F F^T =================
    int sA = 0, sB = 1, sC = 2;          // slots of chunks ch, ch+1, ch+2
    for (int ch = 0; ch < NCH; ++ch) {
        if (ch + 3 < NCH) stage(ch + 3, sA);          // reuse conv(ch)'s slot
        if (ch + 1 < NCH) convert(sB, (ch + 1) & 1);  // co-scheduled with MFMA
        mfma_step(ch & 1);
        LGKM0();
        if (ch + 3 < NCH) { VMCNT(4); } else { VMCNT(0); }
        SCHED0();
        __builtin_amdgcn_s_barrier();
        const int tmp = sA; sA = sB; sB = sC; sC = tmp;
    }

    // ===== inverse norms from the diagonal (compile-time acc indices) =====
#pragma unroll
    for (int rb = 0; rb < 4; ++rb) {
        const int rowbase = wr * 64 + rb * 16;
#pragma unroll
        for (int cb = 0; cb < 8; ++cb) {
            const int colbase = wc * 128 + cb * 16;
            if (rowbase == colbase) {              // wave-uniform
#pragma unroll
                for (int r = 0; r < 4; ++r) {
                    if (hi * 4 + r == lo)
                        invn[rowbase + hi * 4 + r] = 1.0f / sqrtf(acc[rb][cb][r]);
                }
            }
        }
    }
    __syncthreads();

    // ===== P = C * invn_r * invn_c * Wsym[r][c], in registers =====
#pragma unroll
    for (int rb = 0; rb < 4; ++rb) {
        const int rbase = wr * 64 + rb * 16 + hi * 4;
        const float4 ir4 = *reinterpret_cast<const float4*>(&invn[rbase]);
        const float ir[4] = {ir4.x, ir4.y, ir4.z, ir4.w};
#pragma unroll
        for (int cb = 0; cb < 8; ++cb) {
            const int col = wc * 128 + cb * 16 + lo;
            const float ic = invn[col];
            if (USE_WS) {
#pragma unroll
                for (int r = 0; r < 4; ++r) {
                    const float ws = wsym[(rbase + r) * Nn + col];  // coalesced, L2-hot
                    acc[rb][cb][r] = acc[rb][cb][r] * ir[r] * ic * ws;
                }
            } else {
                const float4 wt = *reinterpret_cast<const float4*>(&W[col * Nn + rbase]);
                const float wtr[4] = {wt.x, wt.y, wt.z, wt.w};
#pragma unroll
                for (int r = 0; r < 4; ++r) {
                    const float ws = 0.5f * (W[(rbase + r) * Nn + col] + wtr[r]);
                    acc[rb][cb][r] = acc[rb][cb][r] * ir[r] * ic * ws;
                }
            }
        }
    }

    // ================= 10 mean-field iterations =================
    // P symmetric -> e[col] = sum_row P[row][col]*s[row]: in-lane over 16 rows,
    // butterfly over hi-groups, LDS partials over the 4 wr row-blocks.
    for (int itr = 0; itr < NITER; ++itr) {
        if (t < Nn) {
            const float x = lgv[t];
            svec[t] = 2.f / (1.f + __expf(-x)) - 1.f;
        }
        __syncthreads();

        float ep[8] = {0.f, 0.f, 0.f, 0.f, 0.f, 0.f, 0.f, 0.f};
#pragma unroll
        for (int rb = 0; rb < 4; ++rb) {
            const float4 s4 = *reinterpret_cast<const float4*>(
                &svec[wr * 64 + rb * 16 + hi * 4]);
#pragma unroll
            for (int cb = 0; cb < 8; ++cb)
                ep[cb] += acc[rb][cb][0] * s4.x + acc[rb][cb][1] * s4.y
                        + acc[rb][cb][2] * s4.z + acc[rb][cb][3] * s4.w;
        }
#pragma unroll
        for (int cb = 0; cb < 8; ++cb) {
            ep[cb] += __shfl_xor(ep[cb], 16);
            ep[cb] += __shfl_xor(ep[cb], 32);
        }
        if (lane < 16) {
#pragma unroll
            for (int cb = 0; cb < 8; ++cb)
                part[wr][wc * 128 + cb * 16 + lane] = ep[cb];
        }
        __syncthreads();
        if (t < Nn)
            lgv[t] = uvec[t] + part[0][t] + part[1][t] + part[2][t] + part[3][t];
    }

    if (t < Nn) out[(size_t)b * Nn + t] = lgv[t];
}

extern "C" void kernel_launch(void* const* d_in, const int* in_sizes, int n_in,
                              void* d_out, int out_size, void* d_ws, size_t ws_size,
                              hipStream_t stream) {
    const float* feats  = (const float*)d_in[0];
    const float* logits = (const float*)d_in[1];
    const float* W      = (const float*)d_in[2];
    float* out = (float*)d_out;

    if (ws_size >= (size_t)Nn * Nn * sizeof(float)) {
        float* wsym = (float*)d_ws;
        wsym_k<<<dim3(64), dim3(256), 0, stream>>>(W, wsym);
        crf_mfma<true><<<dim3(Bb), dim3(512), 0, stream>>>(feats, logits, W, wsym, out);
    } else {
        crf_mfma<false><<<dim3(Bb), dim3(512), 0, stream>>>(feats, logits, W, nullptr, out);
    }
}

// Round 10
// 45.561 us; speedup vs baseline: 1.1236x; 1.1236x over previous
//
#include <hip/hip_runtime.h>
#include <hip/hip_bf16.h>
#include <math.h>

// B=256, N=256, E=512, ITER=10
#define Bb   256
#define Nn   256
#define Ee   512
#define TKF  32             // k-elems per chunk (f32)
#define NCH  (Ee / TKF)     // 16 chunks
#define NITER 10

typedef __attribute__((ext_vector_type(8))) short bf16x8;   // MFMA A/B frag (4 VGPR)
typedef __attribute__((ext_vector_type(4))) float f32x4;    // MFMA C/D frag

#define LGKM0()  asm volatile("s_waitcnt lgkmcnt(0)" ::: "memory")

static __device__ __forceinline__ unsigned short f2bf(float f) {
    __hip_bfloat16 h = __float2bfloat16(f);     // RNE; pairs fuse to v_cvt_pk_bf16_f32
    return __builtin_bit_cast(unsigned short, h);
}

// bf16 tile: [256 rows][32 k], 64 B rows, XOR swizzle byte ^= (row&3)<<4.
// Frag read positions mod 128B spread over 8 distinct 16B slots x 8 lanes
// = full 32-bank coverage (minimum cycles for b128).
static __device__ __forceinline__ bf16x8 ldfrag(const unsigned char* bt, int row, int hi) {
    const int byte = row * 64 + ((hi * 16) ^ ((row & 3) << 4));
    return *reinterpret_cast<const bf16x8*>(bt + byte);
}

// ---------- Wsym = 0.5*(W + W^T): direct version (proven round 7) ----------
__global__ __launch_bounds__(256) void wsym_k(const float* __restrict__ W,
                                              float* __restrict__ wsym) {
    const int idx = blockIdx.x * 256 + threadIdx.x;   // 0..16383
    const int r  = idx >> 6;                          // row 0..255
    const int c0 = (idx & 63) * 4;                    // col group
    const float4 a = *reinterpret_cast<const float4*>(&W[r * Nn + c0]);
    float4 o;
    o.x = 0.5f * (a.x + W[(c0 + 0) * Nn + r]);
    o.y = 0.5f * (a.y + W[(c0 + 1) * Nn + r]);
    o.z = 0.5f * (a.z + W[(c0 + 2) * Nn + r]);
    o.w = 0.5f * (a.w + W[(c0 + 3) * Nn + r]);
    *reinterpret_cast<float4*>(&wsym[r * Nn + c0]) = o;
}

// 512 threads = 8 waves (4x2); wave (wr,wc) owns rows [wr*64,+64) x cols
// [wc*128,+128) of C = F F^T.  acc[4][8] f32x4 = 128 accum regs; all register
// array indices compile-time (rule #20: manual unroll-by-2 with named sA/sB).
//
// K-loop (T14 reg-staging, ONE barrier per chunk):
//   iter ch:  issue global loads chunk ch+2 -> regs   (consumed next iter)
//             cvt regs(ch+1) -> ds_write btile[(ch+1)&1]   (co-schedules
//             mfma(ch) on btile[ch&1]                        with MFMA)
//             lgkmcnt(0); s_barrier     (ds_writes visible; loads stay in flight)
// Hazards: btile[x] write (iter ch) vs mfma read of btile[x] (iter ch-1) are
// separated by barrier(ch-1); mfma(ch+1) reads after barrier(ch). Register
// sets: chunk m lives in s{A,B}[m&1]; overwritten one iter after its cvt.
template <bool USE_WS>
__global__ __launch_bounds__(512, 2) void crf_mfma(
    const float* __restrict__ feats,   // [B, N, E]
    const float* __restrict__ logits,  // [B, N, 1]
    const float* __restrict__ W,       // [1, N, N] (raw; used if !USE_WS)
    const float* __restrict__ wsym,    // [N, N] precomputed 0.5*(W+W^T)
    float* __restrict__ out)           // [B, N, 1]
{
    const int b    = blockIdx.x;
    const int t    = threadIdx.x;
    const int wave = t >> 6;           // 0..7
    const int lane = t & 63;
    const int wr   = wave >> 1;        // 0..3 (64-row block)
    const int wc   = wave & 1;         // 0..1 (128-col block)
    const int lo   = lane & 15;        // C/D col = lo; A/B row = lo
    const int hi   = lane >> 4;        // C/D row = hi*4+reg; A/B k-base = hi*8

    __shared__ unsigned char btile[2][Nn * 64];  // 2 x 16 KB swizzled bf16 tiles
    __shared__ float invn[Nn];
    __shared__ float svec[Nn];
    __shared__ float uvec[Nn];
    __shared__ float lgv[Nn];
    __shared__ float part[4][Nn];

    f32x4 acc[4][8];
#pragma unroll
    for (int i = 0; i < 4; ++i)
#pragma unroll
        for (int j = 0; j < 8; ++j) acc[i][j] = (f32x4){0.f, 0.f, 0.f, 0.f};

    const float* Fb = feats + (size_t)b * Nn * Ee;

    // per-thread staging geometry (constant across chunks):
    // granule m_i = t + 512*i (16B of f32); row = m>>3, gc = m&7.
    // Global: 8 threads/row, contiguous 128B row-segments (coalesced).
    // ds_write_b64: 64 lanes cover a contiguous 512B span (<=2-way banks).
    const int row0 = t >> 3;           // rows for i: row0 + 64*i
    const int gc   = t & 7;

    float4 sA[4], sB[4];               // two chunk register sets (16 VGPR each)

#define LOADCHUNK(ch, s)                                                    \
    {                                                                       \
        _Pragma("unroll")                                                   \
        for (int i = 0; i < 4; ++i)                                         \
            s[i] = *reinterpret_cast<const float4*>(                        \
                Fb + (size_t)(row0 + 64 * i) * Ee + (ch) * TKF + gc * 4);   \
    }

#define CVTWRITE(s, buf)                                                    \
    {                                                                       \
        _Pragma("unroll")                                                   \
        for (int i = 0; i < 4; ++i) {                                       \
            const int row = row0 + 64 * i;                                  \
            ushort4 pk;                                                     \
            pk.x = f2bf(s[i].x); pk.y = f2bf(s[i].y);                       \
            pk.z = f2bf(s[i].z); pk.w = f2bf(s[i].w);                       \
            *reinterpret_cast<ushort4*>(                                    \
                &btile[buf][row * 64 + ((gc * 8) ^ ((row & 3) << 4))]) = pk;\
        }                                                                   \
    }

    auto mfma_step = [&](int buf) {
        const unsigned char* tb = &btile[buf][0];
        bf16x8 af[4];
#pragma unroll
        for (int rb = 0; rb < 4; ++rb)
            af[rb] = ldfrag(tb, wr * 64 + rb * 16 + lo, hi);
#pragma unroll
        for (int cg = 0; cg < 2; ++cg) {
            bf16x8 bfv[4];
#pragma unroll
            for (int cq = 0; cq < 4; ++cq)
                bfv[cq] = ldfrag(tb, wc * 128 + (cg * 4 + cq) * 16 + lo, hi);
#pragma unroll
            for (int rb = 0; rb < 4; ++rb)
#pragma unroll
                for (int cq = 0; cq < 4; ++cq)
                    acc[rb][cg * 4 + cq] = __builtin_amdgcn_mfma_f32_16x16x32_bf16(
                        af[rb], bfv[cq], acc[rb][cg * 4 + cq], 0, 0, 0);
        }
    };

    // ---- prologue: chunks 0,1 -> regs; cvt chunk0 -> btile[0] ----
    float uval = 0.f;
    if (t < Nn) uval = logits[(size_t)b * Nn + t];
    LOADCHUNK(0, sA);
    LOADCHUNK(1, sB);
    if (t < Nn) {
        uvec[t] = uval;
        lgv[t]  = uval;
    }
    CVTWRITE(sA, 0);                      // waits sA loads only (sB in flight)
    LGKM0();
    __builtin_amdgcn_s_barrier();         // btile[0] visible everywhere

    // ================= GEMM: C = F F^T (unroll-by-2, static reg sets) =========
    for (int ch2 = 0; ch2 < NCH; ch2 += 2) {
        // even ch = ch2: load ch2+2 -> sA; cvt sB (ch2+1) -> btile[1]; mfma btile[0]
        if (ch2 + 2 < NCH) LOADCHUNK(ch2 + 2, sA);
        CVTWRITE(sB, 1);
        mfma_step(0);
        LGKM0();
        __builtin_amdgcn_s_barrier();
        // odd ch = ch2+1: load ch2+3 -> sB; cvt sA (ch2+2) -> btile[0]; mfma btile[1]
        if (ch2 + 3 < NCH) LOADCHUNK(ch2 + 3, sB);
        if (ch2 + 2 < NCH) CVTWRITE(sA, 0);
        mfma_step(1);
        LGKM0();
        __builtin_amdgcn_s_barrier();
    }

    // ===== inverse norms from the diagonal (compile-time acc indices) =====
#pragma unroll
    for (int rb = 0; rb < 4; ++rb) {
        const int rowbase = wr * 64 + rb * 16;
#pragma unroll
        for (int cb = 0; cb < 8; ++cb) {
            const int colbase = wc * 128 + cb * 16;
            if (rowbase == colbase) {              // wave-uniform
#pragma unroll
                for (int r = 0; r < 4; ++r) {
                    if (hi * 4 + r == lo)
                        invn[rowbase + hi * 4 + r] = 1.0f / sqrtf(acc[rb][cb][r]);
                }
            }
        }
    }
    __syncthreads();

    // ===== P = C * invn_r * invn_c * Wsym[r][c], in registers =====
#pragma unroll
    for (int rb = 0; rb < 4; ++rb) {
        const int rbase = wr * 64 + rb * 16 + hi * 4;
        const float4 ir4 = *reinterpret_cast<const float4*>(&invn[rbase]);
        const float ir[4] = {ir4.x, ir4.y, ir4.z, ir4.w};
#pragma unroll
        for (int cb = 0; cb < 8; ++cb) {
            const int col = wc * 128 + cb * 16 + lo;
            const float ic = invn[col];
            if (USE_WS) {
#pragma unroll
                for (int r = 0; r < 4; ++r) {
                    const float ws = wsym[(rbase + r) * Nn + col];  // coalesced, L2-hot
                    acc[rb][cb][r] = acc[rb][cb][r] * ir[r] * ic * ws;
                }
            } else {
                const float4 wt = *reinterpret_cast<const float4*>(&W[col * Nn + rbase]);
                const float wtr[4] = {wt.x, wt.y, wt.z, wt.w};
#pragma unroll
                for (int r = 0; r < 4; ++r) {
                    const float ws = 0.5f * (W[(rbase + r) * Nn + col] + wtr[r]);
                    acc[rb][cb][r] = acc[rb][cb][r] * ir[r] * ic * ws;
                }
            }
        }
    }

    // ================= 10 mean-field iterations =================
    // P symmetric -> e[col] = sum_row P[row][col]*s[row]: in-lane over 16 rows,
    // butterfly over hi-groups, LDS partials over the 4 wr row-blocks.
    for (int itr = 0; itr < NITER; ++itr) {
        if (t < Nn) {
            const float x = lgv[t];
            svec[t] = 2.f / (1.f + __expf(-x)) - 1.f;
        }
        __syncthreads();

        float ep[8] = {0.f, 0.f, 0.f, 0.f, 0.f, 0.f, 0.f, 0.f};
#pragma unroll
        for (int rb = 0; rb < 4; ++rb) {
            const float4 s4 = *reinterpret_cast<const float4*>(
                &svec[wr * 64 + rb * 16 + hi * 4]);
#pragma unroll
            for (int cb = 0; cb < 8; ++cb)
                ep[cb] += acc[rb][cb][0] * s4.x + acc[rb][cb][1] * s4.y
                        + acc[rb][cb][2] * s4.z + acc[rb][cb][3] * s4.w;
        }
#pragma unroll
        for (int cb = 0; cb < 8; ++cb) {
            ep[cb] += __shfl_xor(ep[cb], 16);
            ep[cb] += __shfl_xor(ep[cb], 32);
        }
        if (lane < 16) {
#pragma unroll
            for (int cb = 0; cb < 8; ++cb)
                part[wr][wc * 128 + cb * 16 + lane] = ep[cb];
        }
        __syncthreads();
        if (t < Nn)
            lgv[t] = uvec[t] + part[0][t] + part[1][t] + part[2][t] + part[3][t];
    }

    if (t < Nn) out[(size_t)b * Nn + t] = lgv[t];
#undef LOADCHUNK
#undef CVTWRITE
}

extern "C" void kernel_launch(void* const* d_in, const int* in_sizes, int n_in,
                              void* d_out, int out_size, void* d_ws, size_t ws_size,
                              hipStream_t stream) {
    const float* feats  = (const float*)d_in[0];
    const float* logits = (const float*)d_in[1];
    const float* W      = (const float*)d_in[2];
    float* out = (float*)d_out;

    if (ws_size >= (size_t)Nn * Nn * sizeof(float)) {
        float* wsym = (float*)d_ws;
        wsym_k<<<dim3(64), dim3(256), 0, stream>>>(W, wsym);
        crf_mfma<true><<<dim3(Bb), dim3(512), 0, stream>>>(feats, logits, W, wsym, out);
    } else {
        crf_mfma<false><<<dim3(Bb), dim3(512), 0, stream>>>(feats, logits, W, nullptr, out);
    }
}